// Round 1
// baseline (2545.560 us; speedup 1.0000x reference)
//
#include <hip/hip_runtime.h>

#define TOK 4096   // B*S tokens
#define DIM 2048   // D
#define NEXP 8     // E
#define FF 4096    // F

typedef short short8 __attribute__((ext_vector_type(8)));
typedef float f32x4 __attribute__((ext_vector_type(4)));

__device__ inline ushort f2bf(float f){
  union { float f; unsigned u; } v; v.f = f;
  return (ushort)((v.u + 0x7fffu + ((v.u >> 16) & 1u)) >> 16);
}

__device__ inline void load_lds16(const void* g, void* l){
  __builtin_amdgcn_global_load_lds((const __attribute__((address_space(1))) void*)g,
                                   (__attribute__((address_space(3))) void*)l, 16, 0, 0);
}

// ---------------- router: logits, softmax top-2, per-expert lists ----------------
__global__ void router_kernel(const float* __restrict__ x, const float* __restrict__ Wg,
                              float* __restrict__ logits, int* __restrict__ counts,
                              int* __restrict__ etok, float* __restrict__ ewt){
  int lane = threadIdx.x & 63;
  int wid  = threadIdx.x >> 6;
  int t = blockIdx.x * 4 + wid;          // one wave per token
  const float* xr = x + (size_t)t * DIM;
  float acc[NEXP];
#pragma unroll
  for (int e = 0; e < NEXP; ++e) acc[e] = 0.f;
#pragma unroll
  for (int c = 0; c < DIM/256; ++c){
    int k = c*256 + lane*4;
    float4 xv = *(const float4*)(xr + k);
#pragma unroll
    for (int e = 0; e < NEXP; ++e){
      float4 wv = *(const float4*)(Wg + e*DIM + k);
      acc[e] += xv.x*wv.x + xv.y*wv.y + xv.z*wv.z + xv.w*wv.w;
    }
  }
#pragma unroll
  for (int e = 0; e < NEXP; ++e){
#pragma unroll
    for (int off = 32; off > 0; off >>= 1) acc[e] += __shfl_xor(acc[e], off, 64);
  }
  if (lane == 0){
#pragma unroll
    for (int e = 0; e < NEXP; ++e) logits[(size_t)t*NEXP + e] = acc[e];
    int i0 = 0;
    for (int e = 1; e < NEXP; ++e) if (acc[e] > acc[i0]) i0 = e;
    int i1 = (i0 == 0) ? 1 : 0;
    for (int e = 0; e < NEXP; ++e) if (e != i0 && acc[e] > acc[i1]) i1 = e;
    // normalized top-2 weights (softmax shift cancels)
    float p1 = __expf(acc[i1] - acc[i0]);
    float s = 1.f + p1;
    float w0 = 1.f / s, w1 = p1 / s;
    int pos0 = atomicAdd(&counts[i0], 1);
    etok[i0*TOK + pos0] = (int)((unsigned)t | (i0 < i1 ? 0x80000000u : 0u));
    ewt [i0*TOK + pos0] = w0;
    int pos1 = atomicAdd(&counts[i1], 1);
    etok[i1*TOK + pos1] = (int)((unsigned)t | (i1 < i0 ? 0x80000000u : 0u));
    ewt [i1*TOK + pos1] = w1;
  }
}

// ---------------- gather: expert's token rows of x -> bf16 Ag ----------------
__global__ void gather_kernel(const float* __restrict__ x, const int* __restrict__ counts,
                              const int* __restrict__ etok, ushort* __restrict__ Ag, int e){
  int row = blockIdx.x;
  if (row >= counts[e]) return;
  int t = etok[e*TOK + row] & 0x7fffffff;
  int c = threadIdx.x;                    // 256 chunks of 8 elems
  const float4* src = (const float4*)(x + (size_t)t*DIM + c*8);
  float4 a = src[0], b = src[1];
  ushort o[8] = { f2bf(a.x), f2bf(a.y), f2bf(a.z), f2bf(a.w),
                  f2bf(b.x), f2bf(b.y), f2bf(b.z), f2bf(b.w) };
  *(short8*)(Ag + (size_t)row*DIM + c*8) = *(const short8*)o;
}

// ------- convw: fp32 weights -> bf16 in MFMA-native packed-B 1KB blocks -------
// block (kt over 32-k, nt over 16-n): lane = (n%16) + 16*((k%32)/8), bytes (k%8)*2
__global__ void convw_kernel(const float* __restrict__ W1, const float* __restrict__ W3,
                             const float* __restrict__ W2, ushort* __restrict__ W1P,
                             ushort* __restrict__ W3P, ushort* __restrict__ W2P, int e){
  const int NB = (DIM/32)*(FF/16);        // 16384 blocks per matrix
  int lane = threadIdx.x & 63;
  int bo = blockIdx.x*4 + (threadIdx.x >> 6);
  const float* src; ushort* dst; int Nst;
  if (bo < NB)        { src = W1 + (size_t)e*DIM*FF; dst = W1P; Nst = FF; }
  else if (bo < 2*NB) { bo -= NB;   src = W3 + (size_t)e*DIM*FF; dst = W3P; Nst = FF; }
  else                { bo -= 2*NB; src = W2 + (size_t)e*FF*DIM; dst = W2P; Nst = DIM; }
  int ntn = Nst/16;
  int kt = bo / ntn, nt = bo - kt*ntn;
  int n  = nt*16 + (lane & 15);
  int k0 = kt*32 + ((lane >> 4) << 3);
  ushort o[8];
#pragma unroll
  for (int j = 0; j < 8; ++j) o[j] = f2bf(src[(size_t)(k0+j)*Nst + n]);
  *(short8*)(dst + (size_t)bo*512 + lane*8) = *(const short8*)o;
}

// ---------------- GEMM1: h = silu(Ag@W1) * (Ag@W3), bf16 out ----------------
__global__ __launch_bounds__(256, 2) void gemm1_kernel(const ushort* __restrict__ Ag,
    const ushort* __restrict__ W1P, const ushort* __restrict__ W3P,
    const int* __restrict__ counts, ushort* __restrict__ hbuf, int e){
  int cnt = counts[e];
  int m0 = blockIdx.y * 128;
  if (m0 >= cnt) return;
  int f0 = blockIdx.x * 128;
  __shared__ ushort As[128*72];           // 64+8 pad -> 144B row stride
  __shared__ ushort B1s[8192];            // 16 packed 1KB blocks
  __shared__ ushort B3s[8192];
  int tid = threadIdx.x;
  int lane = tid & 63, wid = tid >> 6;
  int wm = wid >> 1, wn = wid & 1;
  f32x4 z = {0.f, 0.f, 0.f, 0.f};
  f32x4 acc1[4][4], acc3[4][4];
#pragma unroll
  for (int i = 0; i < 4; ++i)
#pragma unroll
    for (int j = 0; j < 4; ++j){ acc1[i][j] = z; acc3[i][j] = z; }

  for (int kt = 0; kt < DIM/64; ++kt){
    int k0 = kt*64;
#pragma unroll
    for (int i = 0; i < 4; ++i){          // stage A (128x64 bf16) via VGPR
      int id = tid + i*256;
      int row = id >> 3, kc = id & 7;
      short8 v = *(const short8*)(Ag + (size_t)(m0+row)*DIM + k0 + kc*8);
      *(short8*)(As + row*72 + kc*8) = v;
    }
#pragma unroll
    for (int i = 0; i < 4; ++i){          // stage B1,B3 via global_load_lds x16B
      int bi = wid + i*4;
      int ktl = bi >> 3, ntl = bi & 7;
      size_t gb = ((size_t)(kt*2 + ktl)*(FF/16) + ((size_t)blockIdx.x*8 + ntl)) * 512;
      load_lds16(W1P + gb + lane*8, B1s + bi*512);
      load_lds16(W3P + gb + lane*8, B3s + bi*512);
    }
    __syncthreads();
#pragma unroll
    for (int ks = 0; ks < 2; ++ks){
      short8 a[4];
#pragma unroll
      for (int mf = 0; mf < 4; ++mf)
        a[mf] = *(const short8*)(As + (wm*64 + mf*16 + (lane&15))*72 + ks*32 + ((lane>>4)<<3));
#pragma unroll
      for (int nf = 0; nf < 4; ++nf){
        int bi = ks*8 + wn*4 + nf;
        short8 b1 = *(const short8*)(B1s + bi*512 + lane*8);
        short8 b3 = *(const short8*)(B3s + bi*512 + lane*8);
#pragma unroll
        for (int mf = 0; mf < 4; ++mf){
          acc1[mf][nf] = __builtin_amdgcn_mfma_f32_16x16x32_bf16(a[mf], b1, acc1[mf][nf], 0, 0, 0);
          acc3[mf][nf] = __builtin_amdgcn_mfma_f32_16x16x32_bf16(a[mf], b3, acc3[mf][nf], 0, 0, 0);
        }
      }
    }
    __syncthreads();
  }
  // epilogue: h = silu(c1)*c3 -> bf16  (C/D: col=lane&15, row=(lane>>4)*4+reg)
  int colb = f0 + wn*64 + (lane & 15);
  int rowb = m0 + wm*64 + ((lane >> 4) << 2);
#pragma unroll
  for (int mf = 0; mf < 4; ++mf){
#pragma unroll
    for (int r = 0; r < 4; ++r){
      int row = rowb + mf*16 + r;
      if (row < cnt){
#pragma unroll
        for (int nf = 0; nf < 4; ++nf){
          float c1 = acc1[mf][nf][r], c3 = acc3[mf][nf][r];
          float h = c1 / (1.f + __expf(-c1)) * c3;
          hbuf[(size_t)row*FF + colb + nf*16] = f2bf(h);
        }
      }
    }
  }
}

// ------------- GEMM2: y[t] (+)= w * (hbuf @ W2), scatter by token -------------
__global__ __launch_bounds__(256, 2) void gemm2_kernel(const ushort* __restrict__ hbuf,
    const ushort* __restrict__ W2P, const int* __restrict__ counts,
    const int* __restrict__ etok, const float* __restrict__ ewt,
    float* __restrict__ y, int e){
  int cnt = counts[e];
  int m0 = blockIdx.y * 128;
  if (m0 >= cnt) return;
  int d0 = blockIdx.x * 128;
  __shared__ ushort As[128*72];
  __shared__ ushort Bs[8192];
  int tid = threadIdx.x;
  int lane = tid & 63, wid = tid >> 6;
  int wm = wid >> 1, wn = wid & 1;
  f32x4 z = {0.f, 0.f, 0.f, 0.f};
  f32x4 acc[4][4];
#pragma unroll
  for (int i = 0; i < 4; ++i)
#pragma unroll
    for (int j = 0; j < 4; ++j) acc[i][j] = z;

  for (int kt = 0; kt < FF/64; ++kt){
    int k0 = kt*64;
#pragma unroll
    for (int i = 0; i < 4; ++i){
      int id = tid + i*256;
      int row = id >> 3, kc = id & 7;
      short8 v = *(const short8*)(hbuf + (size_t)(m0+row)*FF + k0 + kc*8);
      *(short8*)(As + row*72 + kc*8) = v;
    }
#pragma unroll
    for (int i = 0; i < 4; ++i){
      int bi = wid + i*4;
      int ktl = bi >> 3, ntl = bi & 7;
      size_t gb = ((size_t)(kt*2 + ktl)*(DIM/16) + ((size_t)blockIdx.x*8 + ntl)) * 512;
      load_lds16(W2P + gb + lane*8, Bs + bi*512);
    }
    __syncthreads();
#pragma unroll
    for (int ks = 0; ks < 2; ++ks){
      short8 a[4];
#pragma unroll
      for (int mf = 0; mf < 4; ++mf)
        a[mf] = *(const short8*)(As + (wm*64 + mf*16 + (lane&15))*72 + ks*32 + ((lane>>4)<<3));
#pragma unroll
      for (int nf = 0; nf < 4; ++nf){
        int bi = ks*8 + wn*4 + nf;
        short8 b = *(const short8*)(Bs + bi*512 + lane*8);
#pragma unroll
        for (int mf = 0; mf < 4; ++mf)
          acc[mf][nf] = __builtin_amdgcn_mfma_f32_16x16x32_bf16(a[mf], b, acc[mf][nf], 0, 0, 0);
      }
    }
    __syncthreads();
  }
  int colb = d0 + wn*64 + (lane & 15);
  int rowb = m0 + wm*64 + ((lane >> 4) << 2);
#pragma unroll
  for (int mf = 0; mf < 4; ++mf){
#pragma unroll
    for (int r = 0; r < 4; ++r){
      int row = rowb + mf*16 + r;
      if (row < cnt){
        int v = etok[e*TOK + row];
        int t = v & 0x7fffffff;
        float w = ewt[e*TOK + row];
        bool first = (v < 0);             // this expert is the token's lower-index expert
        float* yr = y + (size_t)t*DIM;
#pragma unroll
        for (int nf = 0; nf < 4; ++nf){
          float val = acc[mf][nf][r] * w;
          int col = colb + nf*16;
          if (first) yr[col] = val;       // first (earlier launch) writes
          else       yr[col] += val;      // second adds — no race: sequential launches
        }
      }
    }
  }
}

extern "C" void kernel_launch(void* const* d_in, const int* in_sizes, int n_in,
                              void* d_out, int out_size, void* d_ws, size_t ws_size,
                              hipStream_t stream){
  const float* x  = (const float*)d_in[0];
  const float* Wg = (const float*)d_in[1];
  const float* W1 = (const float*)d_in[2];
  const float* W3 = (const float*)d_in[3];
  const float* W2 = (const float*)d_in[4];
  float* y      = (float*)d_out;
  float* logits = y + (size_t)TOK*DIM;

  char* ws = (char*)d_ws;
  size_t off = 0;
  auto alloc = [&](size_t b)->char*{ char* p = ws + off; off += (b + 255) & ~(size_t)255; return p; };
  int*    counts = (int*)   alloc(NEXP*sizeof(int));
  int*    etok   = (int*)   alloc((size_t)NEXP*TOK*sizeof(int));
  float*  ewt    = (float*) alloc((size_t)NEXP*TOK*sizeof(float));
  ushort* Ag     = (ushort*)alloc((size_t)TOK*DIM*2);     // 16.8 MB
  ushort* hbuf   = (ushort*)alloc((size_t)TOK*FF*2);      // 33.6 MB
  ushort* W1P    = (ushort*)alloc((size_t)DIM*FF*2);      // 16.8 MB
  ushort* W3P    = (ushort*)alloc((size_t)DIM*FF*2);      // 16.8 MB
  ushort* W2P    = (ushort*)alloc((size_t)FF*DIM*2);      // 16.8 MB  -> ~101 MB total

  hipMemsetAsync(counts, 0, NEXP*sizeof(int), stream);
  router_kernel<<<TOK/4, 256, 0, stream>>>(x, Wg, logits, counts, etok, ewt);
  for (int e = 0; e < NEXP; ++e){
    gather_kernel<<<TOK, 256, 0, stream>>>(x, counts, etok, Ag, e);
    convw_kernel<<<3*(DIM/32)*(FF/16)/4, 256, 0, stream>>>(W1, W3, W2, W1P, W3P, W2P, e);
    gemm1_kernel<<<dim3(FF/128, TOK/128), 256, 0, stream>>>(Ag, W1P, W3P, counts, hbuf, e);
    gemm2_kernel<<<dim3(DIM/128, TOK/128), 256, 0, stream>>>(hbuf, W2P, counts, etok, ewt, y, e);
  }
}